// Round 8
// baseline (2413.912 us; speedup 1.0000x reference)
//
#include <hip/hip_runtime.h>
#include <hip/hip_bf16.h>

// AudioLSTM fused persistent kernel, v16: TWO INTERLEAVED GROUPS PER BLOCK.
// B=512, T=1000, IN=26, H1=64, H2=32, FC 32->16->10.
// 16 blocks x 512 threads (8 waves), TWO independent 16-elem groups (X,Y).
// v15 post-mortem: staging never set the pace (v13 burst ~= v14 smooth);
// compute waves run ~1900cy/step with ~60% dependency stall, phase-locked by
// the per-step barrier. v16 fills the stall holes with a second independent
// recurrence chain IN THE SAME WAVES:
//   wv0-3: LSTM1(X) + LSTM1(Y) interleaved (frag reads together, 24 MFMA,
//          acts X then Y) -- Y's issue fills X's chain stalls in-order.
//   wv4-5: LSTM2(X) halves;  wv6-7: LSTM2(Y) halves.
//   staging: 52 rows/step spread across all 8 waves (<=7 lanes each), loads
//   at iter top, LDS writes at iter bottom (HBM latency hidden; nothing in
//   flight at the barrier -- v15's drain problem gone).
// One barrier per iteration now serves TWO group-steps.
// Math identical to v11..v15: f16 MFMA frags, prescaled gates, pair-rcp acts.

typedef __hip_bfloat16 bf16;
typedef _Float16 f16;
typedef _Float16 f16x8 __attribute__((ext_vector_type(8)));
typedef _Float16 f16x4 __attribute__((ext_vector_type(4)));
typedef float    f32x4 __attribute__((ext_vector_type(4)));

#define T_STEPS 1000
#define IN_DIM  26
#define EPB     16      // batch elems per group
#define CH      16      // staged x chunk length (timesteps)
#define NCHUNK  62      // last chunk index = (T_STEPS-1)/CH
#define H1P     72      // padded h1 row (f16): 144B
#define H2P     40      // padded h2 row (f16): 80B
#define XP      40      // padded Xst row (f16): 80B

#define NL2E  -1.4426950408889634f   // -log2(e): i,f,o gate prescale
#define N2L2E -2.8853900817779268f   // -2log2(e): g gate prescale

__device__ __forceinline__ float bits2f(unsigned short h) {
    return __uint_as_float(((unsigned int)h) << 16);
}
__device__ __forceinline__ float ldv(const void* p, long i, bool isb) {
    return isb ? bits2f(((const unsigned short*)p)[i]) : ((const float*)p)[i];
}
__device__ __forceinline__ float rcp_(float x) { return __builtin_amdgcn_rcpf(x); }
__device__ __forceinline__ float ex2_(float x) { return __builtin_amdgcn_exp2f(x); }

// Prescaled pre-activations (yi=-log2e*pi, yg=-2log2e*pg, ...).
// Updates c, returns h = sigm(o)*tanh(c). 5 exp2 + 3 rcp + ~13 VALU.
__device__ __forceinline__ float lstm_act(float yi, float yf, float yg,
                                          float yo, float& c) {
    const float A  = ex2_(yi), F = ex2_(yf), B = ex2_(yg), O = ex2_(yo);
    const float a1 = 1.f + A, f1 = 1.f + F, b1 = 1.f + B, o1 = 1.f + O;
    const float ig = (2.f - b1) * rcp_(a1 * b1);     // sigm(i)*tanh(g)
    c = fmaf(rcp_(f1), c, ig);                       // f*c + i*g
    const float C2  = ex2_(N2L2E * c);               // e^(-2c)
    const float c1p = 1.f + C2;
    return (2.f - c1p) * rcp_(o1 * c1p);             // sigm(o)*tanh(c)
}

#define MFMA(a, b, c) __builtin_amdgcn_mfma_f32_16x16x32_f16((a), (b), (c), 0, 0, 0)

__global__
__attribute__((amdgpu_flat_work_group_size(512, 512), amdgpu_waves_per_eu(2, 2)))
void lstm_fused(const void* __restrict__ x,
                const void* __restrict__ w_ih1, const void* __restrict__ w_hh1,
                const void* __restrict__ b_ih1, const void* __restrict__ b_hh1,
                const void* __restrict__ w_ih2, const void* __restrict__ w_hh2,
                const void* __restrict__ b_ih2, const void* __restrict__ b_hh2,
                const void* __restrict__ w_fc1, const void* __restrict__ b_fc1,
                const void* __restrict__ w_fc2, const void* __restrict__ b_fc2,
                void* __restrict__ out)
{
    const int tid  = threadIdx.x;      // 0..511
    const int lane = tid & 63;
    const int wv   = tid >> 6;         // 0..7
    const int ecol = lane & 15;        // MFMA N-col = elem within group
    const int g4   = lane >> 4;        // lane group 0..3
    const int r15  = lane & 15;
    const int e00  = blockIdx.x * (2 * EPB);

    __shared__ __align__(16) f16   Xst[2][2][CH][EPB][XP];  // [grp][buf] 80KB
    __shared__ __align__(16) f16   H1T[2][2][EPB][H1P];     // [grp][parity]
    __shared__ __align__(16) f16   H2T[2][2][EPB][H2P];
    __shared__ __align__(16) float f1s[2][EPB][16];

    // ---- runtime dtype detection (uniform): w_ih1 ~ U(-1/8,1/8) ----
    bool isb = true;
    {
        const unsigned short* wu = (const unsigned short*)w_ih1;
        for (int k = 0; k < 64; ++k) {
            float v = fabsf(bits2f(wu[k]));
            if (!(v <= 0.1251f)) isb = false;
        }
    }

    // ---- zero LDS (x k-pad, h pads, h1[-1]=h2[-1]=0) ----
    {
        float4 z; z.x = z.y = z.z = z.w = 0.f;
        float4* p = (float4*)&Xst[0][0][0][0][0];
        for (int k = tid; k < (int)(sizeof(Xst) / 16); k += 512) p[k] = z;
        float4* q = (float4*)&H1T[0][0][0][0];
        for (int k = tid; k < (int)(sizeof(H1T) / 16); k += 512) q[k] = z;
        float4* r = (float4*)&H2T[0][0][0][0];
        for (int k = tid; k < (int)(sizeof(H2T) / 16); k += 512) r[k] = z;
    }

    // ---- role weight fragments (A-frag: row = lane&15, k = 8*g4+j) ----
    // wv0-3: LSTM1 unit-group wv (shared by groups X,Y -- same weights).
    // wv4-7: LSTM2 half (wv-4)&1; wv4,5 -> group X; wv6,7 -> group Y.
    f16x8 W8[8]; f16x8 W4[4]; f32x4 C4[4];
    if (wv < 4) {
#pragma unroll
        for (int gi = 0; gi < 4; ++gi) {
            const float sc = (gi == 2) ? N2L2E : NL2E;
            const int R = gi * 64 + 16 * wv + r15;
#pragma unroll
            for (int k0 = 0; k0 < 2; ++k0)
#pragma unroll
                for (int jj = 0; jj < 8; ++jj)
                    W8[gi * 2 + k0][jj] =
                        (f16)(sc * ldv(w_hh1, R * 64 + k0 * 32 + g4 * 8 + jj, isb));
#pragma unroll
            for (int jj = 0; jj < 8; ++jj) {
                const int k = g4 * 8 + jj;
                W4[gi][jj] =
                    (f16)(k < IN_DIM ? sc * ldv(w_ih1, R * IN_DIM + k, isb) : 0.f);
            }
#pragma unroll
            for (int jj = 0; jj < 4; ++jj) {
                const int Rc = gi * 64 + 16 * wv + g4 * 4 + jj;
                C4[gi][jj] = sc * (ldv(b_ih1, Rc, isb) + ldv(b_hh1, Rc, isb));
            }
        }
    } else {
        const int hf = (wv - 4) & 1;
#pragma unroll
        for (int gi = 0; gi < 4; ++gi) {
            const float sc = (gi == 2) ? N2L2E : NL2E;
            const int R = gi * 32 + 16 * hf + r15;
#pragma unroll
            for (int k0 = 0; k0 < 2; ++k0)
#pragma unroll
                for (int jj = 0; jj < 8; ++jj)
                    W8[gi * 2 + k0][jj] =
                        (f16)(sc * ldv(w_ih2, R * 64 + k0 * 32 + g4 * 8 + jj, isb));
#pragma unroll
            for (int jj = 0; jj < 8; ++jj)
                W4[gi][jj] = (f16)(sc * ldv(w_hh2, R * 32 + g4 * 8 + jj, isb));
#pragma unroll
            for (int jj = 0; jj < 4; ++jj) {
                const int Rc = gi * 32 + 16 * hf + g4 * 4 + jj;
                C4[gi][jj] = sc * (ldv(b_ih2, Rc, isb) + ldv(b_hh2, Rc, isb));
            }
        }
    }

    __syncthreads();   // LDS zeroed before staging overwrites i<26

    // sync stage of one (g, e,i) row of chunk c (prologue only)
    auto stageP = [&](int g, int p, int c) {
        const int t0 = c * CH;
        const int nt = (T_STEPS - t0 < CH) ? (T_STEPS - t0) : CH;
        const int e = p / IN_DIM, i = p - e * IN_DIM;
        const long gb = ((long)(e00 + g * EPB + e) * IN_DIM + i) * T_STEPS + t0;
        float4 fb[4];
        if (isb) {
            const float4* q = (const float4*)((const unsigned short*)x + gb);
            fb[0] = q[0]; if (nt > 8) fb[1] = q[1];
        } else {
            const float4* q = (const float4*)((const float*)x + gb);
            fb[0] = q[0]; fb[1] = q[1];
            if (nt > 8) { fb[2] = q[2]; fb[3] = q[3]; }
        }
#pragma unroll
        for (int t = 0; t < CH; ++t) if (t < nt) {
            float v;
            if (isb) {
                unsigned int u =
                    __builtin_bit_cast(unsigned int, fb[t >> 3][(t >> 1) & 3]);
                v = bits2f((t & 1) ? (unsigned short)(u >> 16)
                                   : (unsigned short)(u & 0xffffu));
            } else {
                v = fb[t >> 2][t & 3];
            }
            Xst[g][c & 1][t][e][i] = (f16)v;
        }
    };

    // prologue: chunk 0 both groups (832 rows) + chunk 1 slice 0 (52 rows)
    for (int r = tid; r < 2 * EPB * IN_DIM; r += 512)
        stageP(r / (EPB * IN_DIM), r % (EPB * IN_DIM), 0);
    if (tid >= 460) {
        const int r = tid - 460;                 // 0..51
        stageP(r / IN_DIM, r % IN_DIM, 1);       // slice 0 -> e=0, i=r%26
    }
    __syncthreads();

    // xg[0] into registers for both groups (LSTM1 waves)
    f32x4 xgcX[4], xgcY[4];
    if (wv < 4) {
        const f16x8 xfX = *(const f16x8*)&Xst[0][0][0][ecol][g4 * 8];
        const f16x8 xfY = *(const f16x8*)&Xst[1][0][0][ecol][g4 * 8];
#pragma unroll
        for (int gi = 0; gi < 4; ++gi) {
            xgcX[gi] = MFMA(W4[gi], xfX, C4[gi]);
            xgcY[gi] = MFMA(W4[gi], xfY, C4[gi]);
        }
    }

    float c1X[4] = {0.f, 0.f, 0.f, 0.f};   // LSTM1: X / Y cell states
    float c1Y[4] = {0.f, 0.f, 0.f, 0.f};
    float cst[4] = {0.f, 0.f, 0.f, 0.f};   // LSTM2 cell state (wv4-7)

    // staging lane map: row = wv + 8*lane, active iff row < 52
    const int srow = wv + 8 * lane;
    const bool stl = (srow < 52);
    const int sG = stl ? (srow / IN_DIM) : 0;        // group
    const int sI = stl ? (srow - sG * IN_DIM) : 0;   // feature i

    for (int s = 0; s <= T_STEPS; ++s) {
        const int pc = s & 1, pp = pc ^ 1;

        // ---- staging loads issued at iteration top (all waves) ----
        const int s1 = s + 1, cS = (s1 >> 4) + 1;
        const bool doS = stl && (cS <= NCHUNK);
        float4 fbS[4];
        int eS = 0, ntS = CH;
        if (doS) {
            eS = s1 & 15;                            // slice = elem
            const int t0S = cS * CH;
            ntS = (T_STEPS - t0S < CH) ? (T_STEPS - t0S) : CH;
            const long gb =
                ((long)(e00 + sG * EPB + eS) * IN_DIM + sI) * T_STEPS + t0S;
            if (isb) {
                const float4* q = (const float4*)((const unsigned short*)x + gb);
                fbS[0] = q[0]; if (ntS > 8) fbS[1] = q[1];
            } else {
                const float4* q = (const float4*)((const float*)x + gb);
                fbS[0] = q[0]; fbS[1] = q[1];
                if (ntS > 8) { fbS[2] = q[2]; fbS[3] = q[3]; }
            }
        }

        if (wv < 4) {
            // ==== LSTM1 X and Y, interleaved (two independent chains) ====
            if (s < T_STEPS) {
                const f16x8 h1f0X = *(const f16x8*)&H1T[0][pp][ecol][g4 * 8];
                const f16x8 h1f1X = *(const f16x8*)&H1T[0][pp][ecol][32 + g4 * 8];
                const f16x8 h1f0Y = *(const f16x8*)&H1T[1][pp][ecol][g4 * 8];
                const f16x8 h1f1Y = *(const f16x8*)&H1T[1][pp][ecol][32 + g4 * 8];
                const bool nx = (s + 1 < T_STEPS);
                f16x8 xfX = {}, xfY = {};
                if (nx) {
                    const int sn = s + 1, nb = (sn >> 4) & 1, nt = sn & 15;
                    xfX = *(const f16x8*)&Xst[0][nb][nt][ecol][g4 * 8];
                    xfY = *(const f16x8*)&Xst[1][nb][nt][ecol][g4 * 8];
                }
                f32x4 gtX[4], gtY[4];
#pragma unroll
                for (int gi = 0; gi < 4; ++gi) {
                    f32x4 tX = MFMA(W8[gi * 2 + 0], h1f0X, xgcX[gi]);
                    gtX[gi]  = MFMA(W8[gi * 2 + 1], h1f1X, tX);
                    f32x4 tY = MFMA(W8[gi * 2 + 0], h1f0Y, xgcY[gi]);
                    gtY[gi]  = MFMA(W8[gi * 2 + 1], h1f1Y, tY);
                }
                if (nx) {
#pragma unroll
                    for (int gi = 0; gi < 4; ++gi) {
                        xgcX[gi] = MFMA(W4[gi], xfX, C4[gi]);
                        xgcY[gi] = MFMA(W4[gi], xfY, C4[gi]);
                    }
                }
                f16x4 hhX, hhY;
#pragma unroll
                for (int jj = 0; jj < 4; ++jj) {      // unit 16*wv + 4*g4 + jj
                    hhX[jj] = (f16)lstm_act(gtX[0][jj], gtX[1][jj],
                                            gtX[2][jj], gtX[3][jj], c1X[jj]);
                    hhY[jj] = (f16)lstm_act(gtY[0][jj], gtY[1][jj],
                                            gtY[2][jj], gtY[3][jj], c1Y[jj]);
                }
                *(f16x4*)&H1T[0][pc][ecol][16 * wv + g4 * 4] = hhX;
                *(f16x4*)&H1T[1][pc][ecol][16 * wv + g4 * 4] = hhY;
            }
        } else {
            // ==== LSTM2 step s-1: wv4-5 -> group X, wv6-7 -> group Y ====
            if (s >= 1) {
                const int g  = (wv >= 6) ? 1 : 0;
                const int hf = (wv - 4) & 1;
                const f16x8 h1f0 = *(const f16x8*)&H1T[g][pp][ecol][g4 * 8];
                const f16x8 h1f1 = *(const f16x8*)&H1T[g][pp][ecol][32 + g4 * 8];
                const f16x8 h2f  = *(const f16x8*)&H2T[g][pc][ecol][g4 * 8];
                f32x4 gt[4];
#pragma unroll
                for (int gi = 0; gi < 4; ++gi) {
                    f32x4 t0 = MFMA(W8[gi * 2 + 0], h1f0, C4[gi]);
                    t0       = MFMA(W8[gi * 2 + 1], h1f1, t0);
                    gt[gi]   = MFMA(W4[gi], h2f, t0);
                }
                f16x4 hh;
#pragma unroll
                for (int jj = 0; jj < 4; ++jj)        // unit 16*hf + 4*g4 + jj
                    hh[jj] = (f16)lstm_act(gt[0][jj], gt[1][jj],
                                           gt[2][jj], gt[3][jj], cst[jj]);
                *(f16x4*)&H2T[g][pp][ecol][16 * hf + g4 * 4] = hh;   // h2[s-1]
            }
        }

        // ---- staging writes at iteration bottom (latency hidden above) ----
        if (doS) {
            const int bf = cS & 1;
#pragma unroll
            for (int t = 0; t < CH; ++t) if (t < ntS) {
                float v;
                if (isb) {
                    unsigned int u =
                        __builtin_bit_cast(unsigned int, fbS[t >> 3][(t >> 1) & 3]);
                    v = bits2f((t & 1) ? (unsigned short)(u >> 16)
                                       : (unsigned short)(u & 0xffffu));
                } else {
                    v = fbS[t >> 2][t & 3];
                }
                Xst[sG][bf][t][eS][sI] = (f16)v;
            }
        }

        __syncthreads();
    }

    // ---- FC head: h2[T-1] in H2T[g][1] (written at s=1000, pp=1) ----
    {
        const int g = tid >> 8, r = tid & 255;
        const int e = r >> 4, o = r & 15;
        float ss = ldv(b_fc1, o, isb);
#pragma unroll 8
        for (int k = 0; k < 32; ++k)
            ss = fmaf(ldv(w_fc1, o * 32 + k, isb), (float)H2T[g][1][e][k], ss);
        f1s[g][e][o] = fmaxf(ss, 0.f);
    }
    __syncthreads();
    if (tid < 320) {
        const int g = tid / 160, r = tid - g * 160;
        const int e = r / 10, o = r - e * 10;
        float ss = ldv(b_fc2, o, isb);
#pragma unroll
        for (int k = 0; k < 16; ++k)
            ss = fmaf(ldv(w_fc2, o * 16 + k, isb), f1s[g][e][k], ss);
        const long oi = (long)(e00 + g * EPB + e) * 10 + o;
        if (isb) ((bf16*)out)[oi] = __float2bfloat16(ss);
        else     ((float*)out)[oi] = ss;
    }
}

extern "C" void kernel_launch(void* const* d_in, const int* in_sizes, int n_in,
                              void* d_out, int out_size, void* d_ws, size_t ws_size,
                              hipStream_t stream) {
    lstm_fused<<<dim3(512 / (2 * EPB)), dim3(512), 0, stream>>>(
        d_in[0], d_in[1], d_in[2], d_in[3], d_in[4],
        d_in[5], d_in[6], d_in[7], d_in[8],
        d_in[9], d_in[10], d_in[11], d_in[12], d_out);
}

// Round 9
// 1121.326 us; speedup vs baseline: 2.1527x; 2.1527x over previous
//
#include <hip/hip_runtime.h>
#include <hip/hip_bf16.h>

// AudioLSTM fused persistent kernel, v17: 4-WAVE CONSOLIDATED (1 wave/SIMD).
// B=512, T=1000, IN=26, H1=64, H2=32, FC 32->16->10.
// 32 blocks x 256 threads (4 waves), one 16-elem group per block.
// Evidence v9/v13/v14: per-step time pinned ~1900-2200cy across decomposi-
// tions with >=8 waves; v16 (more work/wave) 3x worse. Untested: minimum
// wave count. v17 puts EVERYTHING in 4 waves (no intra-SIMD contention,
// cheapest barrier):
//   wave wv: LSTM1 unit-group wv (8 MFMA + 4 acts) + in-reg xg (4 MFMA)
//          + LSTM2 tile (wv&1), acts jj-half (wv>>1) (12 MFMA redundant-pair,
//            2 acts) -> 6 acts/lane/wave, perfectly balanced trans load.
//   h1 frag reads SHARED between LSTM1-hh and LSTM2-ih (same lane mapping).
//   x staged in 16-step bursts by all 4 waves (v13 pattern).
// Acts: 7-trans form (was 8): one rcp serves f-gate and ig denominators:
//   c' = R*(c*P + (2-b1)*f1), R = rcp(P*f1), P = a1*b1  [exact algebra].
// f16 MFMA frags, prescaled gates -- math otherwise identical to v14.

typedef __hip_bfloat16 bf16;
typedef _Float16 f16;
typedef _Float16 f16x8 __attribute__((ext_vector_type(8)));
typedef _Float16 f16x4 __attribute__((ext_vector_type(4)));
typedef _Float16 f16x2 __attribute__((ext_vector_type(2)));
typedef float    f32x4 __attribute__((ext_vector_type(4)));

#define T_STEPS 1000
#define IN_DIM  26
#define EPB     16      // batch elems per block/group
#define CH      16      // staged x chunk length (timesteps)
#define H1P     72      // padded h1 row (f16): 144B
#define H2P     40      // padded h2 row (f16): 80B
#define XP      40      // padded Xst row (f16): 80B

#define NL2E  -1.4426950408889634f   // -log2(e): i,f,o gate prescale
#define N2L2E -2.8853900817779268f   // -2log2(e): g gate prescale

__device__ __forceinline__ float bits2f(unsigned short h) {
    return __uint_as_float(((unsigned int)h) << 16);
}
__device__ __forceinline__ float ldv(const void* p, long i, bool isb) {
    return isb ? bits2f(((const unsigned short*)p)[i]) : ((const float*)p)[i];
}
__device__ __forceinline__ float rcp_(float x) { return __builtin_amdgcn_rcpf(x); }
__device__ __forceinline__ float ex2_(float x) { return __builtin_amdgcn_exp2f(x); }

// Prescaled pre-activations (yi=-log2e*pi, yg=-2log2e*pg, ...).
// Updates c, returns h = sigm(o)*tanh(c). 5 exp2 + 2 rcp + ~16 VALU.
// c' = c/f1 + (1-B)/((1+A)(1+B)) = R*(c*P + (2-b1)*f1), R=rcp(P*f1), P=a1*b1.
__device__ __forceinline__ float lstm_act(float yi, float yf, float yg,
                                          float yo, float& c) {
    const float A  = ex2_(yi), F = ex2_(yf), B = ex2_(yg), O = ex2_(yo);
    const float a1 = 1.f + A, f1 = 1.f + F, b1 = 1.f + B, o1 = 1.f + O;
    const float P  = a1 * b1;
    const float R  = rcp_(P * f1);
    c = R * fmaf(c, P, (2.f - b1) * f1);             // f*c + i*g
    const float C2  = ex2_(N2L2E * c);               // e^(-2c)
    const float c1p = 1.f + C2;
    return (2.f - c1p) * rcp_(o1 * c1p);             // sigm(o)*tanh(c)
}

#define MFMA(a, b, c) __builtin_amdgcn_mfma_f32_16x16x32_f16((a), (b), (c), 0, 0, 0)

__global__
__attribute__((amdgpu_flat_work_group_size(256, 256), amdgpu_waves_per_eu(1, 1)))
void lstm_fused(const void* __restrict__ x,
                const void* __restrict__ w_ih1, const void* __restrict__ w_hh1,
                const void* __restrict__ b_ih1, const void* __restrict__ b_hh1,
                const void* __restrict__ w_ih2, const void* __restrict__ w_hh2,
                const void* __restrict__ b_ih2, const void* __restrict__ b_hh2,
                const void* __restrict__ w_fc1, const void* __restrict__ b_fc1,
                const void* __restrict__ w_fc2, const void* __restrict__ b_fc2,
                void* __restrict__ out)
{
    const int tid  = threadIdx.x;      // 0..255
    const int lane = tid & 63;
    const int wv   = tid >> 6;         // 0..3 : LSTM1 unit-group
    const int hf   = wv & 1;           // LSTM2 tile (units 16hf..16hf+15)
    const int jh   = wv >> 1;          // LSTM2 act jj-half
    const int ecol = lane & 15;        // MFMA N-col = elem within group
    const int g4   = lane >> 4;        // lane group 0..3
    const int r15  = lane & 15;
    const int e0   = blockIdx.x * EPB;

    __shared__ __align__(16) f16   Xst[2][CH][EPB][XP];  // 40960 B
    __shared__ __align__(16) f16   H1T[2][EPB][H1P];     // 4608 B
    __shared__ __align__(16) f16   H2T[2][EPB][H2P];     // 2560 B
    __shared__ __align__(16) float f1s[EPB][16];         // 1024 B

    // ---- runtime dtype detection (uniform): w_ih1 ~ U(-1/8,1/8) ----
    bool isb = true;
    {
        const unsigned short* wu = (const unsigned short*)w_ih1;
        for (int k = 0; k < 64; ++k) {
            float v = fabsf(bits2f(wu[k]));
            if (!(v <= 0.1251f)) isb = false;
        }
    }

    // ---- zero LDS (x k-pad, h pads, h1[-1]=h2[-1]=0) ----
    {
        float4 z; z.x = z.y = z.z = z.w = 0.f;
        float4* p = (float4*)&Xst[0][0][0][0];
        for (int k = tid; k < (int)(sizeof(Xst) / 16); k += 256) p[k] = z;
        float4* q = (float4*)&H1T[0][0][0];
        for (int k = tid; k < (int)(sizeof(H1T) / 16); k += 256) q[k] = z;
        float4* r = (float4*)&H2T[0][0][0];
        for (int k = tid; k < (int)(sizeof(H2T) / 16); k += 256) r[k] = z;
    }

    // ---- weight fragments, BOTH roles per wave (A-frag: row=lane&15,
    //      k=8*g4+j). LSTM1 group wv; LSTM2 tile hf. ----
    f16x8 Whh1A[8]; f16x8 Wih1A[4]; f32x4 b1C[4];
    f16x8 Wih2A[8]; f16x8 Whh2A[4]; f32x4 b2C[4];
#pragma unroll
    for (int gi = 0; gi < 4; ++gi) {
        const float sc = (gi == 2) ? N2L2E : NL2E;
        {   // LSTM1: rows gi*64 + 16*wv + r15
            const int R = gi * 64 + 16 * wv + r15;
#pragma unroll
            for (int k0 = 0; k0 < 2; ++k0)
#pragma unroll
                for (int jj = 0; jj < 8; ++jj)
                    Whh1A[gi * 2 + k0][jj] =
                        (f16)(sc * ldv(w_hh1, R * 64 + k0 * 32 + g4 * 8 + jj, isb));
#pragma unroll
            for (int jj = 0; jj < 8; ++jj) {
                const int k = g4 * 8 + jj;
                Wih1A[gi][jj] =
                    (f16)(k < IN_DIM ? sc * ldv(w_ih1, R * IN_DIM + k, isb) : 0.f);
            }
#pragma unroll
            for (int jj = 0; jj < 4; ++jj) {
                const int Rc = gi * 64 + 16 * wv + g4 * 4 + jj;
                b1C[gi][jj] = sc * (ldv(b_ih1, Rc, isb) + ldv(b_hh1, Rc, isb));
            }
        }
        {   // LSTM2: rows gi*32 + 16*hf + r15
            const int R = gi * 32 + 16 * hf + r15;
#pragma unroll
            for (int k0 = 0; k0 < 2; ++k0)
#pragma unroll
                for (int jj = 0; jj < 8; ++jj)
                    Wih2A[gi * 2 + k0][jj] =
                        (f16)(sc * ldv(w_ih2, R * 64 + k0 * 32 + g4 * 8 + jj, isb));
#pragma unroll
            for (int jj = 0; jj < 8; ++jj)
                Whh2A[gi][jj] = (f16)(sc * ldv(w_hh2, R * 32 + g4 * 8 + jj, isb));
#pragma unroll
            for (int jj = 0; jj < 4; ++jj) {
                const int Rc = gi * 32 + 16 * hf + g4 * 4 + jj;
                b2C[gi][jj] = sc * (ldv(b_ih2, Rc, isb) + ldv(b_hh2, Rc, isb));
            }
        }
    }

    __syncthreads();   // LDS zeroed before staging overwrites i<26

    // stage one (e,i) row of chunk c: 16 timesteps, wide loads (burst)
    auto stageRow = [&](int p, int c) {
        const int t0 = c * CH;
        const int nt = (T_STEPS - t0 < CH) ? (T_STEPS - t0) : CH;
        const int e = p / IN_DIM, i = p - e * IN_DIM;
        const long gb = ((long)(e0 + e) * IN_DIM + i) * T_STEPS + t0;
        float4 fb[4];
        if (isb) {
            const float4* q = (const float4*)((const unsigned short*)x + gb);
            fb[0] = q[0]; if (nt > 8) fb[1] = q[1];
        } else {
            const float4* q = (const float4*)((const float*)x + gb);
            fb[0] = q[0]; fb[1] = q[1];
            if (nt > 8) { fb[2] = q[2]; fb[3] = q[3]; }
        }
#pragma unroll
        for (int t = 0; t < CH; ++t) if (t < nt) {
            float v;
            if (isb) {
                unsigned int u =
                    __builtin_bit_cast(unsigned int, fb[t >> 3][(t >> 1) & 3]);
                v = bits2f((t & 1) ? (unsigned short)(u >> 16)
                                   : (unsigned short)(u & 0xffffu));
            } else {
                v = fb[t >> 2][t & 3];
            }
            Xst[c & 1][t][e][i] = (f16)v;
        }
    };

    // prologue: chunk 0 (416 rows over 256 threads)
    for (int p = tid; p < EPB * IN_DIM; p += 256) stageRow(p, 0);
    __syncthreads();

    // xg[0] into registers (all waves; C-layout, prescaled bias folded in)
    f32x4 xgc[4];
    {
        const f16x8 xf = *(const f16x8*)&Xst[0][0][ecol][g4 * 8];
#pragma unroll
        for (int gi = 0; gi < 4; ++gi) xgc[gi] = MFMA(Wih1A[gi], xf, b1C[gi]);
    }

    float c1s[4] = {0.f, 0.f, 0.f, 0.f};   // LSTM1 cells (4 units/lane)
    float c2s[2] = {0.f, 0.f};             // LSTM2 cells (2 units/lane)

    for (int s = 0; s <= T_STEPS; ++s) {
        const int pc = s & 1, pp = pc ^ 1;

        // ---- shared LDS frag reads (h1 used by LSTM1-hh AND LSTM2-ih) ----
        const f16x8 h1f0 = *(const f16x8*)&H1T[pp][ecol][g4 * 8];
        const f16x8 h1f1 = *(const f16x8*)&H1T[pp][ecol][32 + g4 * 8];
        const f16x8 h2f  = *(const f16x8*)&H2T[pc][ecol][g4 * 8];  // h2[s-2]
        const bool nx = (s + 1 < T_STEPS);
        f16x8 xf = {};
        if (nx) {
            const int sn = s + 1;
            xf = *(const f16x8*)&Xst[(sn >> 4) & 1][sn & 15][ecol][g4 * 8];
        }

        // ---- MFMA blocks ----
        f32x4 gt1[4], xgn[4], gt2[4];
        if (s < T_STEPS) {
#pragma unroll
            for (int gi = 0; gi < 4; ++gi) {
                f32x4 t0 = MFMA(Whh1A[gi * 2 + 0], h1f0, xgc[gi]);  // C = xg
                gt1[gi]  = MFMA(Whh1A[gi * 2 + 1], h1f1, t0);
            }
            if (nx) {
#pragma unroll
                for (int gi = 0; gi < 4; ++gi)
                    xgn[gi] = MFMA(Wih1A[gi], xf, b1C[gi]);          // xg[s+1]
            }
        }
        if (s >= 1) {                       // LSTM2 step s-1 (tile hf)
#pragma unroll
            for (int gi = 0; gi < 4; ++gi) {
                f32x4 t0 = MFMA(Wih2A[gi * 2 + 0], h1f0, b2C[gi]);
                t0       = MFMA(Wih2A[gi * 2 + 1], h1f1, t0);
                gt2[gi]  = MFMA(Whh2A[gi], h2f, t0);
            }
        }

        // ---- activations ----
        if (s < T_STEPS) {
            f16x4 hh;
#pragma unroll
            for (int jj = 0; jj < 4; ++jj)            // unit 16*wv + 4*g4 + jj
                hh[jj] = (f16)lstm_act(gt1[0][jj], gt1[1][jj],
                                       gt1[2][jj], gt1[3][jj], c1s[jj]);
            *(f16x4*)&H1T[pc][ecol][16 * wv + g4 * 4] = hh;
            if (nx) {
#pragma unroll
                for (int gi = 0; gi < 4; ++gi) xgc[gi] = xgn[gi];
            }
        }
        if (s >= 1) {                       // acts for jj = 2jh, 2jh+1 only
            f16x2 hh;
#pragma unroll
            for (int q = 0; q < 2; ++q) {   // unit 16*hf + 4*g4 + 2*jh + q
                const int jj = 2 * jh + q;
                hh[q] = (f16)lstm_act(gt2[0][jj], gt2[1][jj],
                                      gt2[2][jj], gt2[3][jj], c2s[q]);
            }
            *(f16x2*)&H2T[pp][ecol][16 * hf + g4 * 4 + 2 * jh] = hh;  // h2[s-1]
        }

        // ---- stage next x chunk every CH steps (burst, all threads) ----
        if ((s & (CH - 1)) == 0 && s + CH < T_STEPS) {
            const int c = (s >> 4) + 1;
            for (int p = tid; p < EPB * IN_DIM; p += 256) stageRow(p, c);
        }

        __syncthreads();
    }

    // ---- FC head: h2[T-1] in H2T[1] (written at s=1000, pp=1) ----
    {
        const int e = tid >> 4, o = tid & 15;   // 256 threads = 16e x 16o
        float ss = ldv(b_fc1, o, isb);
#pragma unroll 8
        for (int k = 0; k < 32; ++k)
            ss = fmaf(ldv(w_fc1, o * 32 + k, isb), (float)H2T[1][e][k], ss);
        f1s[e][o] = fmaxf(ss, 0.f);
    }
    __syncthreads();
    if (tid < EPB * 10) {
        const int e = tid / 10, o = tid - e * 10;
        float ss = ldv(b_fc2, o, isb);
#pragma unroll
        for (int k = 0; k < 16; ++k)
            ss = fmaf(ldv(w_fc2, o * 16 + k, isb), f1s[e][k], ss);
        const long oi = (long)(e0 + e) * 10 + o;
        if (isb) ((bf16*)out)[oi] = __float2bfloat16(ss);
        else     ((float*)out)[oi] = ss;
    }
}

extern "C" void kernel_launch(void* const* d_in, const int* in_sizes, int n_in,
                              void* d_out, int out_size, void* d_ws, size_t ws_size,
                              hipStream_t stream) {
    lstm_fused<<<dim3(512 / EPB), dim3(256), 0, stream>>>(
        d_in[0], d_in[1], d_in[2], d_in[3], d_in[4],
        d_in[5], d_in[6], d_in[7], d_in[8],
        d_in[9], d_in[10], d_in[11], d_in[12], d_out);
}